// Round 1
// baseline (2539.417 us; speedup 1.0000x reference)
//
#include <hip/hip_runtime.h>
#include <math.h>

#define NBATCH 512
#define NDIM 256
#define NHID 512
#define NC 32     // NUM_COEFF
#define NTAIL 30  // NC-2
#define NP 64     // NUM_POINTS (Chebyshev)
#define TEV 16
#define MAXIT 10
#define TOLF 0.01f

// ---- workspace layout (in floats) ----
constexpr size_t OFF_TCHEB = 0;         // 64
constexpr size_t OFF_PHIT  = 64;        // [p=64][n=32] = 2048
constexpr size_t OFF_PQ    = 2112;      // PhibTQ [p=64][n pad 32] = 2048
constexpr size_t OFF_PD2I  = 4160;      // [30][2] = 60 (pad 64)
constexpr size_t OFF_M2    = 4224;      // [2][32] = 64
constexpr size_t OFF_INV0  = 4288;      // 4 (pad 16)
constexpr size_t OFF_PHIOUT= 4304;      // [16][32] = 512
constexpr size_t OFF_SCAL  = 4816;      // 16 floats: [0:1]=double accum, [2]=done,[3]=commit,[4]=iters
constexpr size_t OFF_H1    = 4832;      // 512*512
constexpr size_t OFF_YF2I  = 266976;    // [b][2][256]
constexpr size_t OFF_YM2   = 529120;    // [b][30][256]
constexpr size_t OFF_BT    = 4461280;   // [b][30][256]
constexpr size_t OFF_BTN   = 8393440;   // [b][30][256]
constexpr size_t OFF_YG    = 12325600;  // [b][64][256]  (reused as F)
constexpr size_t OFF_HB    = 20714208;  // [b*64][512]
constexpr size_t WS_FLOATS = 37491424;  // ~150 MB

// ---- output layout (floats) ----
constexpr size_t OUT_TEVAL = 0;
constexpr size_t OUT_TRAJ  = 16;
constexpr size_t OUT_DELTA = 16 + (size_t)TEV*NBATCH*NDIM; // 2097168
constexpr size_t OUT_B     = OUT_DELTA + 1;

#define PI_F 3.14159265358979323846f

// ============ setup: spectral operators (1 block, 64 threads) ============
__global__ void setup_kernel(const float* __restrict__ t_eval, float* __restrict__ ws,
                             float* __restrict__ out)
{
    __shared__ float Phi[32][64];
    __shared__ float DPhi[32][64];
    __shared__ float Phib[30][64];
    __shared__ float tc[64];
    __shared__ float DtS[64];
    __shared__ float inv0s[4];
    __shared__ double Gaug[30][60];
    __shared__ int pivS;

    const int tid = threadIdx.x; // 0..63
    const float t0 = t_eval[0], t1 = t_eval[TEV-1];
    const float sgn = (t1 > t0) ? 1.f : -1.f;
    const float t = -sgn * cosf(PI_F * (float)tid / 64.f);
    tc[tid] = t;
    __syncthreads();
    DtS[tid] = ((tid < 63) ? tc[tid+1] : 1.0f) - t;

    // Chebyshev T_k and derivative rows
    {
        float p0 = 1.f, p1 = t;
        Phi[0][tid] = p0; Phi[1][tid] = p1;
        for (int k = 2; k < 32; ++k) { float pk = 2.f*t*p1 - p0; Phi[k][tid] = pk; p0 = p1; p1 = pk; }
        const float sc = 2.f / (t1 - t0);
        float u0 = 1.f, u1 = 2.f*t;
        DPhi[0][tid] = 0.f;
        DPhi[1][tid] = sc * 1.f * u0;
        DPhi[2][tid] = sc * 2.f * u1;
        for (int k = 3; k < 32; ++k) { float uk = 2.f*t*u1 - u0; DPhi[k][tid] = sc * (float)k * uk; u0 = u1; u1 = uk; }
    }
    __syncthreads();

    if (tid == 0) {
        double a = Phi[0][0], b = DPhi[0][0], c = Phi[1][0], d = DPhi[1][0];
        double det = a*d - b*c;
        inv0s[0] = (float)( d/det); inv0s[1] = (float)(-b/det);
        inv0s[2] = (float)(-c/det); inv0s[3] = (float)( a/det);
    }
    __syncthreads();
    if (tid == 0) { ws[OFF_INV0+0]=inv0s[0]; ws[OFF_INV0+1]=inv0s[1]; ws[OFF_INV0+2]=inv0s[2]; ws[OFF_INV0+3]=inv0s[3]; }
    if (tid < 30) {
        float P = Phi[2+tid][0], D = DPhi[2+tid][0];
        ws[OFF_PD2I + tid*2+0] = P*inv0s[0] + D*inv0s[2];
        ws[OFF_PD2I + tid*2+1] = P*inv0s[1] + D*inv0s[3];
    }
    __syncthreads();
    for (int m = 0; m < 30; ++m)
        Phib[m][tid] = DPhi[2+m][tid] - (ws[OFF_PD2I+m*2]*DPhi[0][tid] + ws[OFF_PD2I+m*2+1]*DPhi[1][tid]);
    __syncthreads();

    // G = Phib @ diag(Dt) @ Phib^T  (30x30), augmented with I
    for (int e = tid; e < 900; e += 64) {
        int i = e / 30, j = e % 30;
        double s = 0.0;
        for (int p = 0; p < 64; ++p) s += (double)Phib[i][p] * (double)DtS[p] * (double)Phib[j][p];
        Gaug[i][j] = s;
        Gaug[i][30+j] = (i == j) ? 1.0 : 0.0;
    }
    __syncthreads();

    // Gauss-Jordan inverse (double, partial pivoting)
    for (int k = 0; k < 30; ++k) {
        if (tid == 0) {
            int piv = k; double mx = fabs(Gaug[k][k]);
            for (int i = k+1; i < 30; ++i) { double v = fabs(Gaug[i][k]); if (v > mx) { mx = v; piv = i; } }
            pivS = piv;
        }
        __syncthreads();
        const int piv = pivS;
        if (piv != k)
            for (int j = tid; j < 60; j += 64) { double tmp = Gaug[k][j]; Gaug[k][j] = Gaug[piv][j]; Gaug[piv][j] = tmp; }
        __syncthreads();
        const double pv = Gaug[k][k];
        __syncthreads();
        for (int j = tid; j < 60; j += 64) Gaug[k][j] = Gaug[k][j] / pv;
        __syncthreads();
        double fac[30];
        for (int i = 0; i < 30; ++i) fac[i] = Gaug[i][k];
        __syncthreads();
        for (int i = 0; i < 30; ++i) {
            if (i == k) continue;
            for (int j = tid; j < 60; j += 64) Gaug[i][j] -= fac[i] * Gaug[k][j];
        }
        __syncthreads();
    }

    // PhibTQ[p][n] = Dt[p] * sum_m Phib[m][p] * Q[m][n]
    for (int n = 0; n < 30; ++n) {
        double s = 0.0;
        for (int m = 0; m < 30; ++m) s += (double)Phib[m][tid] * Gaug[m][30+n];
        ws[OFF_PQ + (size_t)tid*32 + n] = (float)((double)DtS[tid] * s);
    }
    ws[OFF_PQ + (size_t)tid*32 + 30] = 0.f;
    ws[OFF_PQ + (size_t)tid*32 + 31] = 0.f;
    __syncthreads();

    // M2[j][n] = inv0[j][0]*A2[0][n] + inv0[j][1]*A2[1][n], A2[j'][n] = sum_p DPhi[j'][p]*PhibTQ[p][n]
    if (tid < 30) {
        double a20 = 0.0, a21 = 0.0;
        for (int p = 0; p < 64; ++p) {
            double pq = (double)ws[OFF_PQ + (size_t)p*32 + tid];
            a20 += (double)DPhi[0][p] * pq;
            a21 += (double)DPhi[1][p] * pq;
        }
        ws[OFF_M2 + 0*32 + tid] = (float)((double)inv0s[0]*a20 + (double)inv0s[1]*a21);
        ws[OFF_M2 + 1*32 + tid] = (float)((double)inv0s[2]*a20 + (double)inv0s[3]*a21);
    }

    // PhiT [p][n], t_cheb
    for (int n = 0; n < 32; ++n) ws[OFF_PHIT + (size_t)tid*32 + n] = Phi[n][tid];
    ws[OFF_TCHEB + tid] = tc[tid];

    // Phi_out [t][n] and t_eval passthrough output
    if (tid < TEV) {
        float te = t_eval[tid];
        out[OUT_TEVAL + tid] = te;
        float tt = -1.f + 2.f*(te - t0)/(t1 - t0);
        float q0 = 1.f, q1 = tt;
        ws[OFF_PHIOUT + (size_t)tid*32 + 0] = q0;
        ws[OFF_PHIOUT + (size_t)tid*32 + 1] = q1;
        for (int k = 2; k < 32; ++k) { float qk = 2.f*tt*q1 - q0; ws[OFF_PHIOUT + (size_t)tid*32 + k] = qk; q0 = q1; q1 = qk; }
    }

    if (tid == 0) {
        double* acc = (double*)(ws + OFF_SCAL);
        acc[0] = 0.0;
        int* ip = (int*)(ws + OFF_SCAL + 2);
        ip[0] = 0;  // done
        ip[1] = 0;  // commit
        ip[2] = 0;  // iters
    }
}

// ============ B_init [b][d][n] -> Bt [b][n][d] ============
__global__ __launch_bounds__(256) void transB_kernel(const float* __restrict__ Bin, float* __restrict__ Bt)
{
    const int t = threadIdx.x, b = blockIdx.x;
    const float* src = Bin + ((size_t)(b*NDIM + t)) * NTAIL;
    #pragma unroll
    for (int n = 0; n < NTAIL; ++n)
        Bt[((size_t)b*NTAIL + n)*NDIM + t] = src[n];
}

// ============ f_init part 1: h1 = tanh(y @ W1 + b1 + t0) ============
__global__ __launch_bounds__(512) void finit_h_kernel(const float* __restrict__ y, const float* __restrict__ W1,
                                                      const float* __restrict__ b1, const float* __restrict__ t_eval,
                                                      float* __restrict__ h1)
{
    __shared__ float ys[NDIM];
    const int t = threadIdx.x, b = blockIdx.x;
    if (t < NDIM) ys[t] = y[(size_t)b*NDIM + t];
    __syncthreads();
    float acc = b1[t] + t_eval[0];
    for (int d = 0; d < NDIM; ++d) acc += ys[d] * W1[(size_t)d*NHID + t];
    h1[(size_t)b*NHID + t] = tanhf(acc);
}

// ============ f_init part 2: f = h1@W2+b2; yf2i, yf2M2t ============
__global__ __launch_bounds__(256) void finit_rest_kernel(const float* __restrict__ y, const float* __restrict__ W2,
                                                         const float* __restrict__ b2, const float* __restrict__ h1,
                                                         const float* __restrict__ inv0, const float* __restrict__ M2,
                                                         float* __restrict__ yf2i, float* __restrict__ yM2)
{
    __shared__ float hs[NHID];
    const int t = threadIdx.x, b = blockIdx.x;
    hs[t] = h1[(size_t)b*NHID + t];
    hs[t+256] = h1[(size_t)b*NHID + 256 + t];
    __syncthreads();
    float f = b2[t];
    for (int h = 0; h < NHID; ++h) f += hs[h] * W2[(size_t)h*NDIM + t];
    const float yv = y[(size_t)b*NDIM + t];
    yf2i[((size_t)b*2 + 0)*NDIM + t] = yv*inv0[0] + f*inv0[2];
    yf2i[((size_t)b*2 + 1)*NDIM + t] = yv*inv0[1] + f*inv0[3];
    #pragma unroll
    for (int n = 0; n < NTAIL; ++n)
        yM2[((size_t)b*NTAIL + n)*NDIM + t] = yv*M2[n] + f*M2[32 + n];
}

// ============ per-iteration: head + y_grid ============
__global__ __launch_bounds__(256) void kernelA(const float* __restrict__ PhiT, const float* __restrict__ pd2i,
                                               const float* __restrict__ yf2i, const float* __restrict__ Bt,
                                               float* __restrict__ Yg, const int* __restrict__ done)
{
    if (*done) return;
    __shared__ float Ps[64][32];
    const int t = threadIdx.x, b = blockIdx.x;
    for (int i = t; i < 2048; i += 256) ((float*)Ps)[i] = PhiT[i];
    __syncthreads();
    float cf[32];
    #pragma unroll
    for (int n = 0; n < NTAIL; ++n) cf[2+n] = Bt[((size_t)b*NTAIL + n)*NDIM + t];
    float c0 = yf2i[((size_t)b*2 + 0)*NDIM + t];
    float c1 = yf2i[((size_t)b*2 + 1)*NDIM + t];
    #pragma unroll
    for (int n = 0; n < NTAIL; ++n) { c0 -= cf[2+n]*pd2i[n*2]; c1 -= cf[2+n]*pd2i[n*2+1]; }
    cf[0] = c0; cf[1] = c1;
    float* yrow = Yg + (size_t)b*NP*NDIM + t;
    for (int p = 0; p < NP; ++p) {
        float s = 0.f;
        #pragma unroll
        for (int k = 0; k < 32; ++k) s += cf[k]*Ps[p][k];
        yrow[(size_t)p*NDIM] = s;
    }
}

// ============ 128x128x16 fp32 GEMM, epi=1: tanh(x+bias+tcheb[row&63]), epi=0: x+bias ============
__global__ __launch_bounds__(256) void gemm_kernel(const float* __restrict__ A, const float* __restrict__ B,
                                                   float* __restrict__ C, int M, int N, int K,
                                                   const float* __restrict__ bias, const float* __restrict__ tcheb,
                                                   const int* __restrict__ done, int epi)
{
    if (done && *done) return;
    __shared__ float As[16][132];
    __shared__ float Bs[16][132];
    const int t = threadIdx.x;
    const int tx = t & 15, ty = t >> 4;
    const int bm = blockIdx.x, bn = blockIdx.y;
    const int row0 = ty*8, col0 = tx*8;
    float acc[8][8];
    #pragma unroll
    for (int i = 0; i < 8; ++i)
        #pragma unroll
        for (int j = 0; j < 8; ++j) acc[i][j] = 0.f;

    const float* Ablk = A + (size_t)bm*128*K;
    const float* Bblk = B + (size_t)bn*128;

    for (int kt = 0; kt < K; kt += 16) {
        #pragma unroll
        for (int i = 0; i < 2; ++i) {
            int idx = t + i*256;
            int r = idx >> 2, c4 = (idx & 3)*4;
            float4 av = *(const float4*)(Ablk + (size_t)r*K + kt + c4);
            As[c4+0][r] = av.x; As[c4+1][r] = av.y; As[c4+2][r] = av.z; As[c4+3][r] = av.w;
        }
        #pragma unroll
        for (int i = 0; i < 2; ++i) {
            int idx = t + i*256;
            int rr = idx >> 5, cc = (idx & 31)*4;
            float4 bv = *(const float4*)(Bblk + (size_t)(kt+rr)*N + cc);
            *(float4*)&Bs[rr][cc] = bv;
        }
        __syncthreads();
        #pragma unroll
        for (int k = 0; k < 16; ++k) {
            float4 a0 = *(const float4*)&As[k][row0];
            float4 a1 = *(const float4*)&As[k][row0+4];
            float4 b0 = *(const float4*)&Bs[k][col0];
            float4 b1v = *(const float4*)&Bs[k][col0+4];
            float a[8] = {a0.x,a0.y,a0.z,a0.w,a1.x,a1.y,a1.z,a1.w};
            float bb[8] = {b0.x,b0.y,b0.z,b0.w,b1v.x,b1v.y,b1v.z,b1v.w};
            #pragma unroll
            for (int i = 0; i < 8; ++i)
                #pragma unroll
                for (int j = 0; j < 8; ++j) acc[i][j] += a[i]*bb[j];
        }
        __syncthreads();
    }

    float bv[8];
    #pragma unroll
    for (int j = 0; j < 8; ++j) bv[j] = bias[bn*128 + col0 + j];
    #pragma unroll
    for (int i = 0; i < 8; ++i) {
        const int r = bm*128 + row0 + i;
        float tadd = (epi == 1) ? tcheb[r & 63] : 0.f;
        float o[8];
        #pragma unroll
        for (int j = 0; j < 8; ++j) {
            float v = acc[i][j] + bv[j] + tadd;
            if (epi == 1) v = tanhf(v);
            o[j] = v;
        }
        float* crow = C + (size_t)r*N + bn*128 + col0;
        *(float4*)(crow)     = make_float4(o[0],o[1],o[2],o[3]);
        *(float4*)(crow + 4) = make_float4(o[4],o[5],o[6],o[7]);
    }
}

// ============ per-iteration: B_new + ||B_new - B||^2 ============
__global__ __launch_bounds__(256) void kernelD(const float* __restrict__ PQ, const float* __restrict__ F,
                                               const float* __restrict__ yM2, const float* __restrict__ Bt,
                                               float* __restrict__ Btn, double* __restrict__ accum,
                                               const int* __restrict__ done)
{
    if (*done) return;
    __shared__ float Qs[64][32];
    __shared__ double red[256];
    const int t = threadIdx.x, b = blockIdx.x;
    for (int i = t; i < 2048; i += 256) ((float*)Qs)[i] = PQ[i];
    __syncthreads();
    float acc[NTAIL];
    #pragma unroll
    for (int n = 0; n < NTAIL; ++n) acc[n] = -yM2[((size_t)b*NTAIL + n)*NDIM + t];
    const float* Fb = F + (size_t)b*NP*NDIM + t;
    for (int p = 0; p < NP; ++p) {
        float f = Fb[(size_t)p*NDIM];
        #pragma unroll
        for (int n = 0; n < NTAIL; ++n) acc[n] += f * Qs[p][n];
    }
    double ss = 0.0;
    #pragma unroll
    for (int n = 0; n < NTAIL; ++n) {
        size_t idx = ((size_t)b*NTAIL + n)*NDIM + t;
        float diff = acc[n] - Bt[idx];
        ss += (double)diff*(double)diff;
        Btn[idx] = acc[n];
    }
    red[t] = ss;
    __syncthreads();
    for (int s2 = 128; s2 > 0; s2 >>= 1) { if (t < s2) red[t] += red[t+s2]; __syncthreads(); }
    if (t == 0) atomicAdd(accum, red[0]);
}

// ============ per-iteration: convergence scalar ============
__global__ void kernelE(double* __restrict__ accum, int* __restrict__ done, int* __restrict__ commit,
                        int* __restrict__ iters, float* __restrict__ outDelta)
{
    if (!*done) {
        float dl = (float)sqrt(*accum);
        *outDelta = dl;
        *commit = 1;
        *iters += 1;
        *accum = 0.0;
        if (dl < TOLF) *done = 1;
    } else {
        *commit = 0;
    }
}

// ============ per-iteration: masked commit Btn -> Bt ============
__global__ __launch_bounds__(256) void kernelF(const int* __restrict__ commit, float* __restrict__ Bt,
                                               const float* __restrict__ Btn)
{
    if (!*commit) return;
    const int t = threadIdx.x, b = blockIdx.x;
    #pragma unroll
    for (int n = 0; n < NTAIL; ++n) {
        size_t idx = ((size_t)b*NTAIL + n)*NDIM + t;
        Bt[idx] = Btn[idx];
    }
}

// ============ epilogue: traj + B output ============
__global__ __launch_bounds__(256) void kernelEpi(const float* __restrict__ PhiOut, const float* __restrict__ pd2i,
                                                 const float* __restrict__ yf2i, const float* __restrict__ Bt,
                                                 float* __restrict__ outTraj, float* __restrict__ outB)
{
    __shared__ float Po[16][32];
    const int t = threadIdx.x, b = blockIdx.x;
    for (int i = t; i < 512; i += 256) ((float*)Po)[i] = PhiOut[i];
    __syncthreads();
    float cf[32];
    #pragma unroll
    for (int n = 0; n < NTAIL; ++n) cf[2+n] = Bt[((size_t)b*NTAIL + n)*NDIM + t];
    float c0 = yf2i[((size_t)b*2 + 0)*NDIM + t];
    float c1 = yf2i[((size_t)b*2 + 1)*NDIM + t];
    #pragma unroll
    for (int n = 0; n < NTAIL; ++n) { c0 -= cf[2+n]*pd2i[n*2]; c1 -= cf[2+n]*pd2i[n*2+1]; }
    cf[0] = c0; cf[1] = c1;
    for (int tt = 0; tt < TEV; ++tt) {
        float s = 0.f;
        #pragma unroll
        for (int k = 0; k < 32; ++k) s += cf[k]*Po[tt][k];
        outTraj[((size_t)tt*NBATCH + b)*NDIM + t] = s;
    }
    float* ob = outB + ((size_t)(b*NDIM + t))*NTAIL;
    #pragma unroll
    for (int n = 0; n < NTAIL; ++n) ob[n] = cf[2+n];
}

extern "C" void kernel_launch(void* const* d_in, const int* in_sizes, int n_in,
                              void* d_out, int out_size, void* d_ws, size_t ws_size,
                              hipStream_t stream)
{
    const float* y_init = (const float*)d_in[0];
    const float* t_eval = (const float*)d_in[1];
    const float* B_init = (const float*)d_in[2];
    const float* W1     = (const float*)d_in[3];
    const float* b1     = (const float*)d_in[4];
    const float* W2     = (const float*)d_in[5];
    const float* b2     = (const float*)d_in[6];
    float* out = (float*)d_out;
    float* ws  = (float*)d_ws;
    if (ws_size < WS_FLOATS * sizeof(float)) return; // workspace too small

    float* tcheb = ws + OFF_TCHEB;
    float* PhiT  = ws + OFF_PHIT;
    float* PQ    = ws + OFF_PQ;
    float* pd2i  = ws + OFF_PD2I;
    float* M2    = ws + OFF_M2;
    float* inv0  = ws + OFF_INV0;
    float* PhiOut= ws + OFF_PHIOUT;
    double* accum = (double*)(ws + OFF_SCAL);
    int* done   = (int*)(ws + OFF_SCAL + 2);
    int* commit = (int*)(ws + OFF_SCAL + 3);
    int* iters  = (int*)(ws + OFF_SCAL + 4);
    float* h1   = ws + OFF_H1;
    float* yf2i = ws + OFF_YF2I;
    float* yM2  = ws + OFF_YM2;
    float* Bt   = ws + OFF_BT;
    float* Btn  = ws + OFF_BTN;
    float* Yg   = ws + OFF_YG;   // also holds F after GEMM2
    float* Hb   = ws + OFF_HB;

    setup_kernel<<<1, 64, 0, stream>>>(t_eval, ws, out);
    transB_kernel<<<NBATCH, 256, 0, stream>>>(B_init, Bt);
    finit_h_kernel<<<NBATCH, 512, 0, stream>>>(y_init, W1, b1, t_eval, h1);
    finit_rest_kernel<<<NBATCH, 256, 0, stream>>>(y_init, W2, b2, h1, inv0, M2, yf2i, yM2);

    const int M = NBATCH * NP; // 32768
    for (int it = 0; it < MAXIT; ++it) {
        kernelA<<<NBATCH, 256, 0, stream>>>(PhiT, pd2i, yf2i, Bt, Yg, done);
        gemm_kernel<<<dim3(M/128, NHID/128), 256, 0, stream>>>(Yg, W1, Hb, M, NHID, NDIM, b1, tcheb, done, 1);
        gemm_kernel<<<dim3(M/128, NDIM/128), 256, 0, stream>>>(Hb, W2, Yg, M, NDIM, NHID, b2, tcheb, done, 0);
        kernelD<<<NBATCH, 256, 0, stream>>>(PQ, Yg, yM2, Bt, Btn, accum, done);
        kernelE<<<1, 1, 0, stream>>>(accum, done, commit, iters, out + OUT_DELTA);
        kernelF<<<NBATCH, 256, 0, stream>>>(commit, Bt, Btn);
    }
    kernelEpi<<<NBATCH, 256, 0, stream>>>(PhiOut, pd2i, yf2i, Bt, out + OUT_TRAJ, out + OUT_B);
}

// Round 2
// 1255.222 us; speedup vs baseline: 2.0231x; 2.0231x over previous
//
#include <hip/hip_runtime.h>
#include <math.h>

#define NBATCH 512
#define NDIM 256
#define NHID 512
#define NC 32
#define NTAIL 30
#define NP 64
#define TEV 16
#define MAXIT 10
#define TOLF 0.01f
#define PI_F 3.14159265358979323846f

typedef __bf16 bf16_t;
typedef __bf16 bf16x8 __attribute__((ext_vector_type(8)));
typedef float f32x4 __attribute__((ext_vector_type(4)));

// ---- workspace layout (float slots) ----
constexpr size_t OFF_TCHEB = 0;
constexpr size_t OFF_PHIT  = 64;
constexpr size_t OFF_PQ    = 2112;
constexpr size_t OFF_PD2I  = 4160;
constexpr size_t OFF_M2    = 4224;
constexpr size_t OFF_INV0  = 4288;
constexpr size_t OFF_PHIOUT= 4304;
constexpr size_t OFF_SCAL  = 4816;
constexpr size_t OFF_H1F   = 4832;                  // 512*512 f32
constexpr size_t OFF_YF2I  = OFF_H1F + 262144;      // [b][2][256] f32
constexpr size_t OFF_YM2   = OFF_YF2I + 262144;     // [b][30][256] f32
constexpr size_t OFF_BT    = OFF_YM2 + 3932160;     // [b][30][256] f32
constexpr size_t OFF_F     = OFF_BT + 3932160;      // [32768][256] f32
constexpr size_t OFF_YGB   = OFF_F + 8388608;       // [32768][256] bf16 (4194304 slots)
constexpr size_t OFF_HB    = OFF_YGB + 4194304;     // [32768][512] bf16 (8388608 slots)
constexpr size_t OFF_W1T   = OFF_HB + 8388608;      // [512][256] bf16
constexpr size_t OFF_W2T   = OFF_W1T + 65536;       // [256][512] bf16
constexpr size_t WS_FLOATS = OFF_W2T + 65536;

// ---- output layout (floats) ----
constexpr size_t OUT_TEVAL = 0;
constexpr size_t OUT_TRAJ  = 16;
constexpr size_t OUT_DELTA = 16 + (size_t)TEV*NBATCH*NDIM;
constexpr size_t OUT_B     = OUT_DELTA + 1;

// async global->LDS 16B
__device__ __forceinline__ void ld16(void* l, const void* g) {
    __builtin_amdgcn_global_load_lds((const __attribute__((address_space(1))) void*)g,
                                     (__attribute__((address_space(3))) void*)l, 16, 0, 0);
}

// ============ setup: spectral operators (1 block, 256 threads) ============
__global__ void setup_kernel(const float* __restrict__ t_eval, float* __restrict__ ws,
                             float* __restrict__ out)
{
    __shared__ float Phi[32][64];
    __shared__ float DPhi[32][64];
    __shared__ float Phib[30][64];
    __shared__ float tcs[64];
    __shared__ float DtS[64];
    __shared__ float inv0s[4];
    __shared__ float pd2s[30][2];
    __shared__ double Gaug[30][61];
    __shared__ double rowk[60];
    __shared__ double colk[30];

    const int tid = threadIdx.x;
    const float t0 = t_eval[0], t1 = t_eval[TEV-1];
    const float sgn = (t1 > t0) ? 1.f : -1.f;

    if (tid < 64) {
        const float t = -sgn * cosf(PI_F * (float)tid / 64.f);
        tcs[tid] = t;
        float p0 = 1.f, p1 = t;
        Phi[0][tid] = p0; Phi[1][tid] = p1;
        for (int k = 2; k < 32; ++k) { float pk = 2.f*t*p1 - p0; Phi[k][tid] = pk; p0 = p1; p1 = pk; }
        const float sc = 2.f / (t1 - t0);
        float u0 = 1.f, u1 = 2.f*t;
        DPhi[0][tid] = 0.f;
        DPhi[1][tid] = sc * 1.f * u0;
        DPhi[2][tid] = sc * 2.f * u1;
        for (int k = 3; k < 32; ++k) { float uk = 2.f*t*u1 - u0; DPhi[k][tid] = sc * (float)k * uk; u0 = u1; u1 = uk; }
    }
    __syncthreads();
    if (tid < 64) DtS[tid] = ((tid < 63) ? tcs[tid+1] : 1.0f) - tcs[tid];
    if (tid == 0) {
        double a = Phi[0][0], b = DPhi[0][0], c = Phi[1][0], d = DPhi[1][0];
        double det = a*d - b*c;
        inv0s[0] = (float)( d/det); inv0s[1] = (float)(-b/det);
        inv0s[2] = (float)(-c/det); inv0s[3] = (float)( a/det);
    }
    __syncthreads();
    if (tid == 0) { ws[OFF_INV0+0]=inv0s[0]; ws[OFF_INV0+1]=inv0s[1]; ws[OFF_INV0+2]=inv0s[2]; ws[OFF_INV0+3]=inv0s[3]; }
    if (tid < 30) {
        float P = Phi[2+tid][0], D = DPhi[2+tid][0];
        float a0 = P*inv0s[0] + D*inv0s[2];
        float a1 = P*inv0s[1] + D*inv0s[3];
        pd2s[tid][0] = a0; pd2s[tid][1] = a1;
        ws[OFF_PD2I + tid*2+0] = a0;
        ws[OFF_PD2I + tid*2+1] = a1;
    }
    __syncthreads();
    if (tid < 64)
        for (int m = 0; m < 30; ++m)
            Phib[m][tid] = DPhi[2+m][tid] - (pd2s[m][0]*DPhi[0][tid] + pd2s[m][1]*DPhi[1][tid]);
    __syncthreads();

    // G = Phib @ diag(Dt) @ Phib^T (SPD), augmented with I
    for (int e = tid; e < 900; e += 256) {
        int i = e / 30, j = e % 30;
        double s = 0.0;
        for (int p = 0; p < 64; ++p) s += (double)Phib[i][p] * (double)DtS[p] * (double)Phib[j][p];
        Gaug[i][j] = s;
        Gaug[i][30+j] = (i == j) ? 1.0 : 0.0;
    }
    __syncthreads();

    // pivotless Gauss-Jordan (SPD), parallel elimination
    for (int k = 0; k < 30; ++k) {
        double invpv = 1.0 / Gaug[k][k];
        if (tid < 60) rowk[tid] = Gaug[k][tid] * invpv;
        if (tid >= 64 && tid < 94) colk[tid-64] = Gaug[tid-64][k];
        __syncthreads();
        for (int e = tid; e < 1800; e += 256) {
            int i = e / 60, j = e - i*60;
            if (i == k) Gaug[i][j] = rowk[j];
            else        Gaug[i][j] -= colk[i] * rowk[j];
        }
        __syncthreads();
    }

    // PhibTQ[p][n] = Dt[p] * sum_m Phib[m][p] * Q[m][n]
    if (tid < 64) {
        for (int n = 0; n < 30; ++n) {
            double s = 0.0;
            for (int m = 0; m < 30; ++m) s += (double)Phib[m][tid] * Gaug[m][30+n];
            ws[OFF_PQ + (size_t)tid*32 + n] = (float)((double)DtS[tid] * s);
        }
        ws[OFF_PQ + (size_t)tid*32 + 30] = 0.f;
        ws[OFF_PQ + (size_t)tid*32 + 31] = 0.f;
    }
    __syncthreads();

    if (tid < 30) {
        double a20 = 0.0, a21 = 0.0;
        for (int p = 0; p < 64; ++p) {
            double pq = (double)ws[OFF_PQ + (size_t)p*32 + tid];
            a20 += (double)DPhi[0][p] * pq;
            a21 += (double)DPhi[1][p] * pq;
        }
        ws[OFF_M2 + 0*32 + tid] = (float)((double)inv0s[0]*a20 + (double)inv0s[1]*a21);
        ws[OFF_M2 + 1*32 + tid] = (float)((double)inv0s[2]*a20 + (double)inv0s[3]*a21);
    }

    if (tid < 64) {
        for (int n = 0; n < 32; ++n) ws[OFF_PHIT + (size_t)tid*32 + n] = Phi[n][tid];
        ws[OFF_TCHEB + tid] = tcs[tid];
    }

    if (tid < TEV) {
        float te = t_eval[tid];
        out[OUT_TEVAL + tid] = te;
        float tt = -1.f + 2.f*(te - t0)/(t1 - t0);
        float q0 = 1.f, q1 = tt;
        ws[OFF_PHIOUT + (size_t)tid*32 + 0] = q0;
        ws[OFF_PHIOUT + (size_t)tid*32 + 1] = q1;
        for (int k = 2; k < 32; ++k) { float qk = 2.f*tt*q1 - q0; ws[OFF_PHIOUT + (size_t)tid*32 + k] = qk; q0 = q1; q1 = qk; }
    }

    if (tid == 0) {
        double* acc = (double*)(ws + OFF_SCAL);
        acc[0] = 0.0;
        int* ip = (int*)(ws + OFF_SCAL + 2);
        ip[0] = 0;  // done
        ip[1] = 0;  // iters
    }
}

// ============ B_init [b][d][n] -> Bt [b][n][d] ============
__global__ __launch_bounds__(256) void transB_kernel(const float* __restrict__ Bin, float* __restrict__ Bt)
{
    const int t = threadIdx.x, b = blockIdx.x;
    const float* src = Bin + ((size_t)(b*NDIM + t)) * NTAIL;
    #pragma unroll
    for (int n = 0; n < NTAIL; ++n)
        Bt[((size_t)b*NTAIL + n)*NDIM + t] = src[n];
}

// ============ W [R][C] f32 -> Wt [C][R] bf16 (64x64 tiles) ============
__global__ __launch_bounds__(256) void transW_kernel(const float* __restrict__ W, bf16_t* __restrict__ Wt,
                                                     int R, int C)
{
    __shared__ float Ls[64][65];
    const int r0 = blockIdx.x*64, c0 = blockIdx.y*64;
    const int lr = threadIdx.x >> 6, lc = threadIdx.x & 63;
    #pragma unroll
    for (int i = 0; i < 16; ++i) {
        int rr = i*4 + lr;
        Ls[rr][lc] = W[(size_t)(r0+rr)*C + c0+lc];
    }
    __syncthreads();
    #pragma unroll
    for (int i = 0; i < 16; ++i) {
        int cc = i*4 + lr;
        Wt[(size_t)(c0+cc)*R + r0 + lc] = (bf16_t)Ls[lc][cc];
    }
}

// ============ f_init part 1 ============
__global__ __launch_bounds__(512) void finit_h_kernel(const float* __restrict__ y, const float* __restrict__ W1,
                                                      const float* __restrict__ b1, const float* __restrict__ t_eval,
                                                      float* __restrict__ h1)
{
    __shared__ float ys[NDIM];
    const int t = threadIdx.x, b = blockIdx.x;
    if (t < NDIM) ys[t] = y[(size_t)b*NDIM + t];
    __syncthreads();
    float acc = b1[t] + t_eval[0];
    for (int d = 0; d < NDIM; ++d) acc += ys[d] * W1[(size_t)d*NHID + t];
    h1[(size_t)b*NHID + t] = tanhf(acc);
}

// ============ f_init part 2 ============
__global__ __launch_bounds__(256) void finit_rest_kernel(const float* __restrict__ y, const float* __restrict__ W2,
                                                         const float* __restrict__ b2, const float* __restrict__ h1,
                                                         const float* __restrict__ inv0, const float* __restrict__ M2,
                                                         float* __restrict__ yf2i, float* __restrict__ yM2)
{
    __shared__ float hs[NHID];
    const int t = threadIdx.x, b = blockIdx.x;
    hs[t] = h1[(size_t)b*NHID + t];
    hs[t+256] = h1[(size_t)b*NHID + 256 + t];
    __syncthreads();
    float f = b2[t];
    for (int h = 0; h < NHID; ++h) f += hs[h] * W2[(size_t)h*NDIM + t];
    const float yv = y[(size_t)b*NDIM + t];
    yf2i[((size_t)b*2 + 0)*NDIM + t] = yv*inv0[0] + f*inv0[2];
    yf2i[((size_t)b*2 + 1)*NDIM + t] = yv*inv0[1] + f*inv0[3];
    #pragma unroll
    for (int n = 0; n < NTAIL; ++n)
        yM2[((size_t)b*NTAIL + n)*NDIM + t] = yv*M2[n] + f*M2[32 + n];
}

// ============ per-iteration: head + y_grid -> bf16 ============
__global__ __launch_bounds__(256) void kernelA(const float* __restrict__ PhiT, const float* __restrict__ pd2i,
                                               const float* __restrict__ yf2i, const float* __restrict__ Bt,
                                               bf16_t* __restrict__ Ygb, const int* __restrict__ done)
{
    if (*done) return;
    __shared__ float Ps[64][32];
    const int t = threadIdx.x, b = blockIdx.x;
    for (int i = t; i < 2048; i += 256) ((float*)Ps)[i] = PhiT[i];
    __syncthreads();
    float cf[32];
    #pragma unroll
    for (int n = 0; n < NTAIL; ++n) cf[2+n] = Bt[((size_t)b*NTAIL + n)*NDIM + t];
    float c0 = yf2i[((size_t)b*2 + 0)*NDIM + t];
    float c1 = yf2i[((size_t)b*2 + 1)*NDIM + t];
    #pragma unroll
    for (int n = 0; n < NTAIL; ++n) { c0 -= cf[2+n]*pd2i[n*2]; c1 -= cf[2+n]*pd2i[n*2+1]; }
    cf[0] = c0; cf[1] = c1;
    bf16_t* yrow = Ygb + (size_t)b*NP*NDIM + t;
    for (int p = 0; p < NP; ++p) {
        float s = 0.f;
        #pragma unroll
        for (int k = 0; k < 32; ++k) s += cf[k]*Ps[p][k];
        yrow[(size_t)p*NDIM] = (bf16_t)s;
    }
}

// ============ bf16 MFMA GEMM 128x128, A[M][K] bf16, Bt[N][K] bf16 ============
// mode 1: C = tanh(A*B + bias + tch[row&63]) -> bf16 ; mode 0: C = A*B + bias -> f32
__global__ __launch_bounds__(256) void mfma_gemm(const bf16_t* __restrict__ A, const bf16_t* __restrict__ Bt,
                                                 void* __restrict__ Cout, const int M, const int N, const int K,
                                                 const float* __restrict__ bias, const float* __restrict__ tch,
                                                 const int* __restrict__ done, const int mode)
{
    if (*done) return;
    __shared__ char smem[21504];
    bf16_t (*As)[32] = (bf16_t(*)[32])smem;
    bf16_t (*Bs)[32] = (bf16_t(*)[32])(smem + 8192);

    const int t = threadIdx.x;
    const int lane = t & 63, w = t >> 6;
    const int wm = w & 1, wn = w >> 1;
    const int fr = lane & 15, quad = lane >> 4;
    const int bm = blockIdx.x, bn = blockIdx.y;

    f32x4 acc[4][4];
    #pragma unroll
    for (int i = 0; i < 4; ++i)
        #pragma unroll
        for (int j = 0; j < 4; ++j)
            acc[i][j] = (f32x4){0.f, 0.f, 0.f, 0.f};

    const int sr = t >> 2;
    const int sc = t & 3;
    const int scA = sc ^ ((sr >> 1) & 3);          // XOR swizzle on global side
    const bf16_t* Ag = A + (size_t)(bm*128 + sr)*K + scA*8;
    const bf16_t* Bg = Bt + (size_t)(bn*128 + sr)*K + scA*8;
    const int ca = (quad ^ ((fr >> 1) & 3)) * 8;   // matching swizzle on read side

    for (int kt = 0; kt < K; kt += 32) {
        ld16(&As[sr][sc*8],    Ag + kt);
        ld16(&As[sr+64][sc*8], Ag + kt + (size_t)64*K);
        ld16(&Bs[sr][sc*8],    Bg + kt);
        ld16(&Bs[sr+64][sc*8], Bg + kt + (size_t)64*K);
        __syncthreads();
        bf16x8 af[4], bf[4];
        #pragma unroll
        for (int i = 0; i < 4; ++i) af[i] = *(const bf16x8*)&As[wm*64 + i*16 + fr][ca];
        #pragma unroll
        for (int j = 0; j < 4; ++j) bf[j] = *(const bf16x8*)&Bs[wn*64 + j*16 + fr][ca];
        #pragma unroll
        for (int i = 0; i < 4; ++i)
            #pragma unroll
            for (int j = 0; j < 4; ++j)
                acc[i][j] = __builtin_amdgcn_mfma_f32_16x16x32_bf16(af[i], bf[j], acc[i][j], 0, 0, 0);
        __syncthreads();
    }

    float bv[4];
    #pragma unroll
    for (int j = 0; j < 4; ++j) bv[j] = bias[bn*128 + wn*64 + j*16 + fr];

    if (mode == 1) {
        bf16_t* H = (bf16_t*)Cout;
        bf16_t (*Hs)[68] = (bf16_t(*)[68])smem;
        for (int h = 0; h < 2; ++h) {
            __syncthreads();
            if (wn == h) {
                #pragma unroll
                for (int i = 0; i < 4; ++i)
                    #pragma unroll
                    for (int j = 0; j < 4; ++j)
                        #pragma unroll
                        for (int r = 0; r < 4; ++r) {
                            int row = wm*64 + i*16 + quad*4 + r;
                            float v = acc[i][j][r] + bv[j] + tch[row & 63];
                            v = fminf(fmaxf(v, -15.f), 15.f);
                            float e = __expf(2.f*v);
                            Hs[row][j*16 + fr] = (bf16_t)((e - 1.f) / (e + 1.f));
                        }
            }
            __syncthreads();
            const int row = t >> 1, seg = t & 1;
            const char* src = (const char*)&Hs[row][seg*32];
            char* dst = (char*)(H + (size_t)(bm*128+row)*N + bn*128 + h*64 + seg*32);
            #pragma unroll
            for (int q = 0; q < 8; ++q)
                *(unsigned long long*)(dst + q*8) = *(const unsigned long long*)(src + q*8);
        }
    } else {
        float* F = (float*)Cout;
        float (*Fs)[42] = (float(*)[42])smem;   // [128][2*21]
        for (int jp = 0; jp < 4; ++jp) {
            __syncthreads();
            #pragma unroll
            for (int i = 0; i < 4; ++i)
                #pragma unroll
                for (int r = 0; r < 4; ++r) {
                    int row = wm*64 + i*16 + quad*4 + r;
                    Fs[row][wn*21 + fr] = acc[i][jp][r] + bv[jp];
                }
            __syncthreads();
            const int row = t & 127, half = t >> 7;
            const float* src = &Fs[row][half*21];
            float* dst = F + (size_t)(bm*128+row)*N + bn*128 + half*64 + jp*16;
            #pragma unroll
            for (int q = 0; q < 4; ++q) {
                float4 v = make_float4(src[q*4], src[q*4+1], src[q*4+2], src[q*4+3]);
                *(float4*)(dst + q*4) = v;
            }
        }
    }
}

// ============ per-iteration: B_new (in place) + ||B_new - B||^2 ============
__global__ __launch_bounds__(256) void kernelD(const float* __restrict__ PQ, const float* __restrict__ F,
                                               const float* __restrict__ yM2, float* __restrict__ Bt,
                                               double* __restrict__ accum, const int* __restrict__ done)
{
    if (*done) return;
    __shared__ float Qs[64][32];
    __shared__ double red[256];
    const int t = threadIdx.x, b = blockIdx.x;
    for (int i = t; i < 2048; i += 256) ((float*)Qs)[i] = PQ[i];
    __syncthreads();
    float acc[NTAIL];
    #pragma unroll
    for (int n = 0; n < NTAIL; ++n) acc[n] = -yM2[((size_t)b*NTAIL + n)*NDIM + t];
    const float* Fb = F + (size_t)b*NP*NDIM + t;
    for (int p = 0; p < NP; ++p) {
        float f = Fb[(size_t)p*NDIM];
        #pragma unroll
        for (int n = 0; n < NTAIL; ++n) acc[n] += f * Qs[p][n];
    }
    double ss = 0.0;
    #pragma unroll
    for (int n = 0; n < NTAIL; ++n) {
        size_t idx = ((size_t)b*NTAIL + n)*NDIM + t;
        float diff = acc[n] - Bt[idx];
        ss += (double)diff*(double)diff;
        Bt[idx] = acc[n];
    }
    red[t] = ss;
    __syncthreads();
    for (int s2 = 128; s2 > 0; s2 >>= 1) { if (t < s2) red[t] += red[t+s2]; __syncthreads(); }
    if (t == 0) atomicAdd(accum, red[0]);
}

// ============ per-iteration: convergence scalar ============
__global__ void kernelE(double* __restrict__ accum, int* __restrict__ done,
                        int* __restrict__ iters, float* __restrict__ outDelta)
{
    if (!*done) {
        float dl = (float)sqrt(*accum);
        *outDelta = dl;
        *iters += 1;
        *accum = 0.0;
        if (dl < TOLF) *done = 1;
    }
}

// ============ epilogue: traj + B output ============
__global__ __launch_bounds__(256) void kernelEpi(const float* __restrict__ PhiOut, const float* __restrict__ pd2i,
                                                 const float* __restrict__ yf2i, const float* __restrict__ Bt,
                                                 float* __restrict__ outTraj, float* __restrict__ outB)
{
    __shared__ float Po[16][32];
    const int t = threadIdx.x, b = blockIdx.x;
    for (int i = t; i < 512; i += 256) ((float*)Po)[i] = PhiOut[i];
    __syncthreads();
    float cf[32];
    #pragma unroll
    for (int n = 0; n < NTAIL; ++n) cf[2+n] = Bt[((size_t)b*NTAIL + n)*NDIM + t];
    float c0 = yf2i[((size_t)b*2 + 0)*NDIM + t];
    float c1 = yf2i[((size_t)b*2 + 1)*NDIM + t];
    #pragma unroll
    for (int n = 0; n < NTAIL; ++n) { c0 -= cf[2+n]*pd2i[n*2]; c1 -= cf[2+n]*pd2i[n*2+1]; }
    cf[0] = c0; cf[1] = c1;
    for (int tt = 0; tt < TEV; ++tt) {
        float s = 0.f;
        #pragma unroll
        for (int k = 0; k < 32; ++k) s += cf[k]*Po[tt][k];
        outTraj[((size_t)tt*NBATCH + b)*NDIM + t] = s;
    }
    float* ob = outB + ((size_t)(b*NDIM + t))*NTAIL;
    #pragma unroll
    for (int n = 0; n < NTAIL; ++n) ob[n] = cf[2+n];
}

extern "C" void kernel_launch(void* const* d_in, const int* in_sizes, int n_in,
                              void* d_out, int out_size, void* d_ws, size_t ws_size,
                              hipStream_t stream)
{
    const float* y_init = (const float*)d_in[0];
    const float* t_eval = (const float*)d_in[1];
    const float* B_init = (const float*)d_in[2];
    const float* W1     = (const float*)d_in[3];
    const float* b1     = (const float*)d_in[4];
    const float* W2     = (const float*)d_in[5];
    const float* b2     = (const float*)d_in[6];
    float* out = (float*)d_out;
    float* ws  = (float*)d_ws;
    if (ws_size < WS_FLOATS * sizeof(float)) return;

    float* tcheb = ws + OFF_TCHEB;
    float* PhiT  = ws + OFF_PHIT;
    float* PQ    = ws + OFF_PQ;
    float* pd2i  = ws + OFF_PD2I;
    float* M2    = ws + OFF_M2;
    float* inv0  = ws + OFF_INV0;
    float* PhiOut= ws + OFF_PHIOUT;
    double* accum = (double*)(ws + OFF_SCAL);
    int* done   = (int*)(ws + OFF_SCAL + 2);
    int* iters  = (int*)(ws + OFF_SCAL + 3);
    float* h1   = ws + OFF_H1F;
    float* yf2i = ws + OFF_YF2I;
    float* yM2  = ws + OFF_YM2;
    float* Bt   = ws + OFF_BT;
    float* F    = ws + OFF_F;
    bf16_t* Ygb = (bf16_t*)(ws + OFF_YGB);
    bf16_t* Hb  = (bf16_t*)(ws + OFF_HB);
    bf16_t* W1t = (bf16_t*)(ws + OFF_W1T);
    bf16_t* W2t = (bf16_t*)(ws + OFF_W2T);

    setup_kernel<<<1, 256, 0, stream>>>(t_eval, ws, out);
    transB_kernel<<<NBATCH, 256, 0, stream>>>(B_init, Bt);
    transW_kernel<<<dim3(NDIM/64, NHID/64), 256, 0, stream>>>(W1, W1t, NDIM, NHID);
    transW_kernel<<<dim3(NHID/64, NDIM/64), 256, 0, stream>>>(W2, W2t, NHID, NDIM);
    finit_h_kernel<<<NBATCH, 512, 0, stream>>>(y_init, W1, b1, t_eval, h1);
    finit_rest_kernel<<<NBATCH, 256, 0, stream>>>(y_init, W2, b2, h1, inv0, M2, yf2i, yM2);

    const int M = NBATCH * NP; // 32768
    for (int it = 0; it < MAXIT; ++it) {
        kernelA<<<NBATCH, 256, 0, stream>>>(PhiT, pd2i, yf2i, Bt, Ygb, done);
        mfma_gemm<<<dim3(M/128, NHID/128), 256, 0, stream>>>(Ygb, W1t, (void*)Hb, M, NHID, NDIM, b1, tcheb, done, 1);
        mfma_gemm<<<dim3(M/128, NDIM/128), 256, 0, stream>>>(Hb, W2t, (void*)F, M, NDIM, NHID, b2, tcheb, done, 0);
        kernelD<<<NBATCH, 256, 0, stream>>>(PQ, F, yM2, Bt, accum, done);
        kernelE<<<1, 1, 0, stream>>>(accum, done, iters, out + OUT_DELTA);
    }
    kernelEpi<<<NBATCH, 256, 0, stream>>>(PhiOut, pd2i, yf2i, Bt, out + OUT_TRAJ, out + OUT_B);
}

// Round 3
// 1130.866 us; speedup vs baseline: 2.2456x; 1.1100x over previous
//
#include <hip/hip_runtime.h>
#include <math.h>

#define NBATCH 512
#define NDIM 256
#define NHID 512
#define NC 32
#define NTAIL 30
#define NP 64
#define TEV 16
#define MAXIT 10
#define TOLF 0.01f
#define PI_F 3.14159265358979323846f

typedef __bf16 bf16_t;
typedef __bf16 bf16x8 __attribute__((ext_vector_type(8)));
typedef float f32x4 __attribute__((ext_vector_type(4)));
typedef unsigned short ushort_t;

// ---- workspace layout (float slots) ----
constexpr size_t OFF_TCHEB = 0;
constexpr size_t OFF_PHIT  = 64;
constexpr size_t OFF_PQ    = 2112;
constexpr size_t OFF_PD2I  = 4160;
constexpr size_t OFF_M2    = 4224;
constexpr size_t OFF_INV0  = 4288;
constexpr size_t OFF_PHIOUT= 4304;
constexpr size_t OFF_SCAL  = 4816;   // [0:1]=double accum, [2]=done, [3]=counter
constexpr size_t OFF_H1F   = 4832;
constexpr size_t OFF_YF2I  = OFF_H1F + 262144;
constexpr size_t OFF_YM2   = OFF_YF2I + 262144;
constexpr size_t OFF_BT    = OFF_YM2 + 3932160;
constexpr size_t OFF_F     = OFF_BT + 3932160;      // unused now
constexpr size_t OFF_YGB   = OFF_F + 8388608;
constexpr size_t OFF_HB    = OFF_YGB + 4194304;
constexpr size_t OFF_W1T   = OFF_HB + 8388608;
constexpr size_t OFF_W2T   = OFF_W1T + 65536;
constexpr size_t OFF_PQBH  = OFF_W2T + 65536;       // [32][64] ushort bf16 hi (1024 floats)
constexpr size_t OFF_PQBL  = OFF_PQBH + 1024;       // lo
constexpr size_t WS_FLOATS = OFF_PQBL + 1024;

// ---- output layout (floats) ----
constexpr size_t OUT_TEVAL = 0;
constexpr size_t OUT_TRAJ  = 16;
constexpr size_t OUT_DELTA = 16 + (size_t)TEV*NBATCH*NDIM;
constexpr size_t OUT_B     = OUT_DELTA + 1;

__device__ __forceinline__ void ld16(void* l, const void* g) {
    __builtin_amdgcn_global_load_lds((const __attribute__((address_space(1))) void*)g,
                                     (__attribute__((address_space(3))) void*)l, 16, 0, 0);
}

__device__ __forceinline__ ushort_t bf16bits(float v) {
    bf16_t h = (bf16_t)v; ushort_t u; __builtin_memcpy(&u, &h, 2); return u;
}

// ============ setup: spectral operators (1 block, 256 threads) ============
__global__ void setup_kernel(const float* __restrict__ t_eval, float* __restrict__ ws,
                             float* __restrict__ out)
{
    __shared__ float Phi[32][64];
    __shared__ float DPhi[32][64];
    __shared__ float Phib[30][64];
    __shared__ float tcs[64];
    __shared__ float DtS[64];
    __shared__ float inv0s[4];
    __shared__ float pd2s[30][2];
    __shared__ double Gs[30][31];

    const int tid = threadIdx.x;
    const float t0 = t_eval[0], t1 = t_eval[TEV-1];
    const float sgn = (t1 > t0) ? 1.f : -1.f;

    if (tid < 64) {
        const float t = -sgn * cosf(PI_F * (float)tid / 64.f);
        tcs[tid] = t;
        float p0 = 1.f, p1 = t;
        Phi[0][tid] = p0; Phi[1][tid] = p1;
        for (int k = 2; k < 32; ++k) { float pk = 2.f*t*p1 - p0; Phi[k][tid] = pk; p0 = p1; p1 = pk; }
        const float sc = 2.f / (t1 - t0);
        float u0 = 1.f, u1 = 2.f*t;
        DPhi[0][tid] = 0.f;
        DPhi[1][tid] = sc * 1.f * u0;
        DPhi[2][tid] = sc * 2.f * u1;
        for (int k = 3; k < 32; ++k) { float uk = 2.f*t*u1 - u0; DPhi[k][tid] = sc * (float)k * uk; u0 = u1; u1 = uk; }
    }
    __syncthreads();
    if (tid < 64) DtS[tid] = ((tid < 63) ? tcs[tid+1] : 1.0f) - tcs[tid];
    if (tid == 0) {
        double a = Phi[0][0], b = DPhi[0][0], c = Phi[1][0], d = DPhi[1][0];
        double det = a*d - b*c;
        inv0s[0] = (float)( d/det); inv0s[1] = (float)(-b/det);
        inv0s[2] = (float)(-c/det); inv0s[3] = (float)( a/det);
    }
    __syncthreads();
    if (tid == 0) { ws[OFF_INV0+0]=inv0s[0]; ws[OFF_INV0+1]=inv0s[1]; ws[OFF_INV0+2]=inv0s[2]; ws[OFF_INV0+3]=inv0s[3]; }
    if (tid < 30) {
        float P = Phi[2+tid][0], D = DPhi[2+tid][0];
        float a0 = P*inv0s[0] + D*inv0s[2];
        float a1 = P*inv0s[1] + D*inv0s[3];
        pd2s[tid][0] = a0; pd2s[tid][1] = a1;
        ws[OFF_PD2I + tid*2+0] = a0;
        ws[OFF_PD2I + tid*2+1] = a1;
    }
    __syncthreads();
    if (tid < 64)
        for (int m = 0; m < 30; ++m)
            Phib[m][tid] = DPhi[2+m][tid] - (pd2s[m][0]*DPhi[0][tid] + pd2s[m][1]*DPhi[1][tid]);
    __syncthreads();

    // G = Phib @ diag(Dt) @ Phib^T (SPD)
    for (int e = tid; e < 900; e += 256) {
        int i = e / 30, j = e % 30;
        double s = 0.0;
        for (int p = 0; p < 64; ++p) s += (double)Phib[i][p] * (double)DtS[p] * (double)Phib[j][p];
        Gs[i][j] = s;
    }
    __syncthreads();

    // Register-resident sweep operator (single wave, no barriers): full sweep of SPD G -> -G^{-1}
    if (tid < 64) {
        const int row = (tid < 30) ? tid : 29;
        double g[30];
        #pragma unroll
        for (int j = 0; j < 30; ++j) g[j] = Gs[row][j];
        #pragma unroll
        for (int k = 0; k < 30; ++k) {
            double d = __shfl(g[k], k, 64);
            double inv = 1.0 / d;
            double fac = g[k];
            bool isk = (tid == k);
            #pragma unroll
            for (int j = 0; j < 30; ++j) {
                double rj = __shfl(g[j], k, 64) * inv;
                g[j] = isk ? rj : (g[j] - fac * rj);
            }
            g[k] = isk ? -inv : fac * inv;
        }
        if (tid < 30) {
            #pragma unroll
            for (int j = 0; j < 30; ++j) Gs[tid][j] = -g[j];   // Q = G^{-1}
        }
    }
    __syncthreads();

    // PhibTQ[p][n] = Dt[p] * sum_m Phib[m][p] * Q[m][n]; also bf16 hi/lo transpose for MFMA stage-2
    if (tid < 64) {
        ushort_t* pqh = (ushort_t*)(ws + OFF_PQBH);
        ushort_t* pql = (ushort_t*)(ws + OFF_PQBL);
        float pqrow[32];
        for (int n = 0; n < 30; ++n) {
            double s = 0.0;
            for (int m = 0; m < 30; ++m) s += (double)Phib[m][tid] * Gs[m][n];
            pqrow[n] = (float)((double)DtS[tid] * s);
        }
        pqrow[30] = 0.f; pqrow[31] = 0.f;
        for (int n = 0; n < 32; ++n) {
            ws[OFF_PQ + (size_t)tid*32 + n] = pqrow[n];
            bf16_t h = (bf16_t)pqrow[n];
            float hf = (float)h;
            pqh[n*64 + tid] = bf16bits(pqrow[n]);
            pql[n*64 + tid] = bf16bits(pqrow[n] - hf);
        }
    }
    __syncthreads();

    if (tid < 30) {
        double a20 = 0.0, a21 = 0.0;
        for (int p = 0; p < 64; ++p) {
            double pq = (double)ws[OFF_PQ + (size_t)p*32 + tid];
            a20 += (double)DPhi[0][p] * pq;
            a21 += (double)DPhi[1][p] * pq;
        }
        ws[OFF_M2 + 0*32 + tid] = (float)((double)inv0s[0]*a20 + (double)inv0s[1]*a21);
        ws[OFF_M2 + 1*32 + tid] = (float)((double)inv0s[2]*a20 + (double)inv0s[3]*a21);
    }

    if (tid < 64) {
        for (int n = 0; n < 32; ++n) ws[OFF_PHIT + (size_t)tid*32 + n] = Phi[n][tid];
        ws[OFF_TCHEB + tid] = tcs[tid];
    }

    if (tid < TEV) {
        float te = t_eval[tid];
        out[OUT_TEVAL + tid] = te;
        float tt = -1.f + 2.f*(te - t0)/(t1 - t0);
        float q0 = 1.f, q1 = tt;
        ws[OFF_PHIOUT + (size_t)tid*32 + 0] = q0;
        ws[OFF_PHIOUT + (size_t)tid*32 + 1] = q1;
        for (int k = 2; k < 32; ++k) { float qk = 2.f*tt*q1 - q0; ws[OFF_PHIOUT + (size_t)tid*32 + k] = qk; q0 = q1; q1 = qk; }
    }

    if (tid == 0) {
        double* acc = (double*)(ws + OFF_SCAL);
        acc[0] = 0.0;
        int* ip = (int*)(ws + OFF_SCAL + 2);
        ip[0] = 0;  // done
        ip[1] = 0;  // block counter
    }
}

// ============ B_init [b][d][n] -> Bt [b][n][d] ============
__global__ __launch_bounds__(256) void transB_kernel(const float* __restrict__ Bin, float* __restrict__ Bt)
{
    const int t = threadIdx.x, b = blockIdx.x;
    const float* src = Bin + ((size_t)(b*NDIM + t)) * NTAIL;
    #pragma unroll
    for (int n = 0; n < NTAIL; ++n)
        Bt[((size_t)b*NTAIL + n)*NDIM + t] = src[n];
}

// ============ W [R][C] f32 -> Wt [C][R] bf16 (64x64 tiles) ============
__global__ __launch_bounds__(256) void transW_kernel(const float* __restrict__ W, bf16_t* __restrict__ Wt,
                                                     int R, int C)
{
    __shared__ float Ls[64][65];
    const int r0 = blockIdx.x*64, c0 = blockIdx.y*64;
    const int lr = threadIdx.x >> 6, lc = threadIdx.x & 63;
    #pragma unroll
    for (int i = 0; i < 16; ++i) {
        int rr = i*4 + lr;
        Ls[rr][lc] = W[(size_t)(r0+rr)*C + c0+lc];
    }
    __syncthreads();
    #pragma unroll
    for (int i = 0; i < 16; ++i) {
        int cc = i*4 + lr;
        Wt[(size_t)(c0+cc)*R + r0 + lc] = (bf16_t)Ls[lc][cc];
    }
}

// ============ f_init part 1 ============
__global__ __launch_bounds__(512) void finit_h_kernel(const float* __restrict__ y, const float* __restrict__ W1,
                                                      const float* __restrict__ b1, const float* __restrict__ t_eval,
                                                      float* __restrict__ h1)
{
    __shared__ float ys[NDIM];
    const int t = threadIdx.x, b = blockIdx.x;
    if (t < NDIM) ys[t] = y[(size_t)b*NDIM + t];
    __syncthreads();
    float acc = b1[t] + t_eval[0];
    for (int d = 0; d < NDIM; ++d) acc += ys[d] * W1[(size_t)d*NHID + t];
    h1[(size_t)b*NHID + t] = tanhf(acc);
}

// ============ f_init part 2 ============
__global__ __launch_bounds__(256) void finit_rest_kernel(const float* __restrict__ y, const float* __restrict__ W2,
                                                         const float* __restrict__ b2, const float* __restrict__ h1,
                                                         const float* __restrict__ inv0, const float* __restrict__ M2,
                                                         float* __restrict__ yf2i, float* __restrict__ yM2)
{
    __shared__ float hs[NHID];
    const int t = threadIdx.x, b = blockIdx.x;
    hs[t] = h1[(size_t)b*NHID + t];
    hs[t+256] = h1[(size_t)b*NHID + 256 + t];
    __syncthreads();
    float f = b2[t];
    for (int h = 0; h < NHID; ++h) f += hs[h] * W2[(size_t)h*NDIM + t];
    const float yv = y[(size_t)b*NDIM + t];
    yf2i[((size_t)b*2 + 0)*NDIM + t] = yv*inv0[0] + f*inv0[2];
    yf2i[((size_t)b*2 + 1)*NDIM + t] = yv*inv0[1] + f*inv0[3];
    #pragma unroll
    for (int n = 0; n < NTAIL; ++n)
        yM2[((size_t)b*NTAIL + n)*NDIM + t] = yv*M2[n] + f*M2[32 + n];
}

// ============ per-iteration: head + y_grid -> bf16 ============
__global__ __launch_bounds__(256) void kernelA(const float* __restrict__ PhiT, const float* __restrict__ pd2i,
                                               const float* __restrict__ yf2i, const float* __restrict__ Bt,
                                               bf16_t* __restrict__ Ygb, const int* __restrict__ done)
{
    if (*done) return;
    __shared__ float Ps[64][32];
    const int t = threadIdx.x, b = blockIdx.x;
    for (int i = t; i < 2048; i += 256) ((float*)Ps)[i] = PhiT[i];
    __syncthreads();
    float cf[32];
    #pragma unroll
    for (int n = 0; n < NTAIL; ++n) cf[2+n] = Bt[((size_t)b*NTAIL + n)*NDIM + t];
    float c0 = yf2i[((size_t)b*2 + 0)*NDIM + t];
    float c1 = yf2i[((size_t)b*2 + 1)*NDIM + t];
    #pragma unroll
    for (int n = 0; n < NTAIL; ++n) { c0 -= cf[2+n]*pd2i[n*2]; c1 -= cf[2+n]*pd2i[n*2+1]; }
    cf[0] = c0; cf[1] = c1;
    bf16_t* yrow = Ygb + (size_t)b*NP*NDIM + t;
    for (int p = 0; p < NP; ++p) {
        float s = 0.f;
        #pragma unroll
        for (int k = 0; k < 32; ++k) s += cf[k]*Ps[p][k];
        yrow[(size_t)p*NDIM] = (bf16_t)s;
    }
}

// ============ GEMM1: bf16 MFMA 128x128, C = tanh(A*W1 + b1 + tch) -> bf16 ============
__global__ __launch_bounds__(256) void mfma_gemm(const bf16_t* __restrict__ A, const bf16_t* __restrict__ Bt,
                                                 void* __restrict__ Cout, const int M, const int N, const int K,
                                                 const float* __restrict__ bias, const float* __restrict__ tch,
                                                 const int* __restrict__ done, const int mode)
{
    if (*done) return;
    __shared__ char smem[21504];
    bf16_t (*As)[32] = (bf16_t(*)[32])smem;
    bf16_t (*Bs)[32] = (bf16_t(*)[32])(smem + 8192);

    const int t = threadIdx.x;
    const int lane = t & 63, w = t >> 6;
    const int wm = w & 1, wn = w >> 1;
    const int fr = lane & 15, quad = lane >> 4;
    const int bm = blockIdx.x, bn = blockIdx.y;

    f32x4 acc[4][4];
    #pragma unroll
    for (int i = 0; i < 4; ++i)
        #pragma unroll
        for (int j = 0; j < 4; ++j)
            acc[i][j] = (f32x4){0.f, 0.f, 0.f, 0.f};

    const int sr = t >> 2;
    const int sc = t & 3;
    const int scA = sc ^ ((sr >> 1) & 3);
    const bf16_t* Ag = A + (size_t)(bm*128 + sr)*K + scA*8;
    const bf16_t* Bg = Bt + (size_t)(bn*128 + sr)*K + scA*8;
    const int ca = (quad ^ ((fr >> 1) & 3)) * 8;

    for (int kt = 0; kt < K; kt += 32) {
        ld16(&As[sr][sc*8],    Ag + kt);
        ld16(&As[sr+64][sc*8], Ag + kt + (size_t)64*K);
        ld16(&Bs[sr][sc*8],    Bg + kt);
        ld16(&Bs[sr+64][sc*8], Bg + kt + (size_t)64*K);
        __syncthreads();
        bf16x8 af[4], bf[4];
        #pragma unroll
        for (int i = 0; i < 4; ++i) af[i] = *(const bf16x8*)&As[wm*64 + i*16 + fr][ca];
        #pragma unroll
        for (int j = 0; j < 4; ++j) bf[j] = *(const bf16x8*)&Bs[wn*64 + j*16 + fr][ca];
        #pragma unroll
        for (int i = 0; i < 4; ++i)
            #pragma unroll
            for (int j = 0; j < 4; ++j)
                acc[i][j] = __builtin_amdgcn_mfma_f32_16x16x32_bf16(af[i], bf[j], acc[i][j], 0, 0, 0);
        __syncthreads();
    }

    float bv[4];
    #pragma unroll
    for (int j = 0; j < 4; ++j) bv[j] = bias[bn*128 + wn*64 + j*16 + fr];

    // tanh epilogue -> bf16 via LDS transpose
    bf16_t* H = (bf16_t*)Cout;
    bf16_t (*Hs)[68] = (bf16_t(*)[68])smem;
    for (int h = 0; h < 2; ++h) {
        __syncthreads();
        if (wn == h) {
            #pragma unroll
            for (int i = 0; i < 4; ++i)
                #pragma unroll
                for (int j = 0; j < 4; ++j)
                    #pragma unroll
                    for (int r = 0; r < 4; ++r) {
                        int row = wm*64 + i*16 + quad*4 + r;
                        float v = acc[i][j][r] + bv[j] + tch[row & 63];
                        v = fminf(fmaxf(v, -15.f), 15.f);
                        float e = __expf(2.f*v);
                        Hs[row][j*16 + fr] = (bf16_t)((e - 1.f) / (e + 1.f));
                    }
        }
        __syncthreads();
        const int row = t >> 1, seg = t & 1;
        const char* src = (const char*)&Hs[row][seg*32];
        char* dst = (char*)(H + (size_t)(bm*128+row)*N + bn*128 + h*64 + seg*32);
        #pragma unroll
        for (int q = 0; q < 8; ++q)
            *(unsigned long long*)(dst + q*8) = *(const unsigned long long*)(src + q*8);
    }
}

// ============ GEMM2 fused: F = H@W2 + b2, then B_new = F@PhibTQ - yM2 (in place) + norm + done ============
__global__ __launch_bounds__(256) void gemm2_fused(const bf16_t* __restrict__ A, const bf16_t* __restrict__ Wt,
                                                   const float* __restrict__ bias,
                                                   const ushort_t* __restrict__ PQhi, const ushort_t* __restrict__ PQlo,
                                                   const float* __restrict__ yM2, float* __restrict__ Bco,
                                                   double* __restrict__ accum, int* __restrict__ counter,
                                                   int* __restrict__ done, float* __restrict__ outDelta)
{
    if (*done) return;
    __shared__ char smem[60416];
    bf16_t (*As)[32] = (bf16_t(*)[32])smem;              // 8192
    bf16_t (*Bs)[32] = (bf16_t(*)[32])(smem + 8192);     // 8192
    unsigned* FsT32  = (unsigned*)(smem + 16384);        // [128][136] bf16 as packed b32, 34816 B
    ushort_t* PQHs   = (ushort_t*)(smem + 51200);        // [32][72] bf16, 4608 B
    ushort_t* PQLs   = (ushort_t*)(smem + 55808);        // [32][72] bf16, 4608 B

    const int t = threadIdx.x;
    const int lane = t & 63, w = t >> 6;
    const int wm = w & 1, wn = w >> 1;
    const int fr = lane & 15, quad = lane >> 4;
    const int bm = blockIdx.x, bn = blockIdx.y;   // bm: 0..255 (2 batches each), bn: 0..1
    const int K = NHID; // 512

    // stage PQ hi/lo into padded LDS (row stride 72)
    {
        int e = t * 8;                   // 0..2040
        int r = e >> 6, c = e & 63;
        uint4 vh = *(const uint4*)(PQhi + e);
        uint4 vl = *(const uint4*)(PQlo + e);
        *(uint4*)(PQHs + r*72 + c) = vh;
        *(uint4*)(PQLs + r*72 + c) = vl;
    }

    f32x4 acc[4][4];
    #pragma unroll
    for (int i = 0; i < 4; ++i)
        #pragma unroll
        for (int j = 0; j < 4; ++j)
            acc[i][j] = (f32x4){0.f, 0.f, 0.f, 0.f};

    const int sr = t >> 2;
    const int sc = t & 3;
    const int scA = sc ^ ((sr >> 1) & 3);
    const bf16_t* Ag = A + (size_t)(bm*128 + sr)*K + scA*8;
    const bf16_t* Bg = Wt + (size_t)(bn*128 + sr)*K + scA*8;
    const int ca = (quad ^ ((fr >> 1) & 3)) * 8;

    for (int kt = 0; kt < K; kt += 32) {
        ld16(&As[sr][sc*8],    Ag + kt);
        ld16(&As[sr+64][sc*8], Ag + kt + (size_t)64*K);
        ld16(&Bs[sr][sc*8],    Bg + kt);
        ld16(&Bs[sr+64][sc*8], Bg + kt + (size_t)64*K);
        __syncthreads();
        bf16x8 af[4], bf[4];
        #pragma unroll
        for (int i = 0; i < 4; ++i) af[i] = *(const bf16x8*)&As[wm*64 + i*16 + fr][ca];
        #pragma unroll
        for (int j = 0; j < 4; ++j) bf[j] = *(const bf16x8*)&Bs[wn*64 + j*16 + fr][ca];
        #pragma unroll
        for (int i = 0; i < 4; ++i)
            #pragma unroll
            for (int j = 0; j < 4; ++j)
                acc[i][j] = __builtin_amdgcn_mfma_f32_16x16x32_bf16(af[i], bf[j], acc[i][j], 0, 0, 0);
        __syncthreads();
    }

    // F tile (+bias) -> LDS transposed [d][r], bf16 packed pairs of rows
    float bv[4];
    #pragma unroll
    for (int j = 0; j < 4; ++j) bv[j] = bias[bn*128 + wn*64 + j*16 + fr];
    #pragma unroll
    for (int i = 0; i < 4; ++i)
        #pragma unroll
        for (int j = 0; j < 4; ++j) {
            const int d = wn*64 + j*16 + fr;
            #pragma unroll
            for (int rp = 0; rp < 2; ++rp) {
                const int r = wm*64 + i*16 + quad*4 + rp*2;
                unsigned u0 = bf16bits(acc[i][j][rp*2]   + bv[j]);
                unsigned u1 = bf16bits(acc[i][j][rp*2+1] + bv[j]);
                FsT32[d*68 + (r>>1)] = u0 | (u1 << 16);
            }
        }
    __syncthreads();

    // stage 2: D2[n][d] = sum_p PQt[n][p] * F[p][d]  (PQ split hi+lo), per batch bb
    const ushort_t* FsTu = (const ushort_t*)(smem + 16384);
    f32x4 acc2[2][2][2];   // [bb][m2][j2]
    #pragma unroll
    for (int bb = 0; bb < 2; ++bb)
        #pragma unroll
        for (int m2 = 0; m2 < 2; ++m2)
            #pragma unroll
            for (int j2 = 0; j2 < 2; ++j2)
                acc2[bb][m2][j2] = (f32x4){0.f, 0.f, 0.f, 0.f};

    #pragma unroll
    for (int kk = 0; kk < 2; ++kk) {
        bf16x8 ah[2], al[2];
        #pragma unroll
        for (int m2 = 0; m2 < 2; ++m2) {
            const int off = (m2*16 + fr)*72 + kk*32 + quad*8;
            ah[m2] = *(const bf16x8*)(PQHs + off);
            al[m2] = *(const bf16x8*)(PQLs + off);
        }
        #pragma unroll
        for (int bb = 0; bb < 2; ++bb)
            #pragma unroll
            for (int j2 = 0; j2 < 2; ++j2) {
                const int d = w*32 + j2*16 + fr;
                bf16x8 bfv = *(const bf16x8*)(FsTu + d*136 + bb*64 + kk*32 + quad*8);
                #pragma unroll
                for (int m2 = 0; m2 < 2; ++m2) {
                    acc2[bb][m2][j2] = __builtin_amdgcn_mfma_f32_16x16x32_bf16(ah[m2], bfv, acc2[bb][m2][j2], 0, 0, 0);
                    acc2[bb][m2][j2] = __builtin_amdgcn_mfma_f32_16x16x32_bf16(al[m2], bfv, acc2[bb][m2][j2], 0, 0, 0);
                }
            }
    }

    // epilogue: B_new = D2 - yM2; diff vs Bco; in-place commit; norm
    double ss = 0.0;
    #pragma unroll
    for (int bb = 0; bb < 2; ++bb)
        #pragma unroll
        for (int m2 = 0; m2 < 2; ++m2)
            #pragma unroll
            for (int j2 = 0; j2 < 2; ++j2)
                #pragma unroll
                for (int rr = 0; rr < 4; ++rr) {
                    const int n = m2*16 + quad*4 + rr;
                    if (n < NTAIL) {
                        const int dg = bn*128 + w*32 + j2*16 + fr;
                        const size_t idx = ((size_t)((bm*2+bb)*NTAIL + n))*NDIM + dg;
                        float val = acc2[bb][m2][j2][rr] - yM2[idx];
                        float old = Bco[idx];
                        float diff = val - old;
                        Bco[idx] = val;
                        ss += (double)diff*(double)diff;
                    }
                }

    #pragma unroll
    for (int off = 32; off > 0; off >>= 1) ss += __shfl_down(ss, off, 64);
    double* redd = (double*)smem;   // As region dead
    if (lane == 0) redd[w] = ss;
    __syncthreads();
    if (t == 0) {
        double tot = redd[0] + redd[1] + redd[2] + redd[3];
        atomicAdd(accum, tot);
        __threadfence();
        int old = atomicAdd(counter, 1);
        if (old == 511) {  // last block of this dispatch
            unsigned long long raw = atomicExch((unsigned long long*)accum, 0ull);
            double total; __builtin_memcpy(&total, &raw, 8);
            float dl = (float)sqrt(total);
            *outDelta = dl;
            *counter = 0;
            if (dl < TOLF) *done = 1;
        }
    }
}

// ============ epilogue: traj + B output ============
__global__ __launch_bounds__(256) void kernelEpi(const float* __restrict__ PhiOut, const float* __restrict__ pd2i,
                                                 const float* __restrict__ yf2i, const float* __restrict__ Bt,
                                                 float* __restrict__ outTraj, float* __restrict__ outB)
{
    __shared__ float Po[16][32];
    const int t = threadIdx.x, b = blockIdx.x;
    for (int i = t; i < 512; i += 256) ((float*)Po)[i] = PhiOut[i];
    __syncthreads();
    float cf[32];
    #pragma unroll
    for (int n = 0; n < NTAIL; ++n) cf[2+n] = Bt[((size_t)b*NTAIL + n)*NDIM + t];
    float c0 = yf2i[((size_t)b*2 + 0)*NDIM + t];
    float c1 = yf2i[((size_t)b*2 + 1)*NDIM + t];
    #pragma unroll
    for (int n = 0; n < NTAIL; ++n) { c0 -= cf[2+n]*pd2i[n*2]; c1 -= cf[2+n]*pd2i[n*2+1]; }
    cf[0] = c0; cf[1] = c1;
    for (int tt = 0; tt < TEV; ++tt) {
        float s = 0.f;
        #pragma unroll
        for (int k = 0; k < 32; ++k) s += cf[k]*Po[tt][k];
        outTraj[((size_t)tt*NBATCH + b)*NDIM + t] = s;
    }
    float* ob = outB + ((size_t)(b*NDIM + t))*NTAIL;
    #pragma unroll
    for (int n = 0; n < NTAIL; ++n) ob[n] = cf[2+n];
}

extern "C" void kernel_launch(void* const* d_in, const int* in_sizes, int n_in,
                              void* d_out, int out_size, void* d_ws, size_t ws_size,
                              hipStream_t stream)
{
    const float* y_init = (const float*)d_in[0];
    const float* t_eval = (const float*)d_in[1];
    const float* B_init = (const float*)d_in[2];
    const float* W1     = (const float*)d_in[3];
    const float* b1     = (const float*)d_in[4];
    const float* W2     = (const float*)d_in[5];
    const float* b2     = (const float*)d_in[6];
    float* out = (float*)d_out;
    float* ws  = (float*)d_ws;
    if (ws_size < WS_FLOATS * sizeof(float)) return;

    float* tcheb = ws + OFF_TCHEB;
    float* PhiT  = ws + OFF_PHIT;
    float* pd2i  = ws + OFF_PD2I;
    float* M2    = ws + OFF_M2;
    float* inv0  = ws + OFF_INV0;
    float* PhiOut= ws + OFF_PHIOUT;
    double* accum = (double*)(ws + OFF_SCAL);
    int* done    = (int*)(ws + OFF_SCAL + 2);
    int* counter = (int*)(ws + OFF_SCAL + 3);
    float* h1   = ws + OFF_H1F;
    float* yf2i = ws + OFF_YF2I;
    float* yM2  = ws + OFF_YM2;
    float* Bt   = ws + OFF_BT;
    bf16_t* Ygb = (bf16_t*)(ws + OFF_YGB);
    bf16_t* Hb  = (bf16_t*)(ws + OFF_HB);
    bf16_t* W1t = (bf16_t*)(ws + OFF_W1T);
    bf16_t* W2t = (bf16_t*)(ws + OFF_W2T);
    ushort_t* pqh = (ushort_t*)(ws + OFF_PQBH);
    ushort_t* pql = (ushort_t*)(ws + OFF_PQBL);

    setup_kernel<<<1, 256, 0, stream>>>(t_eval, ws, out);
    transB_kernel<<<NBATCH, 256, 0, stream>>>(B_init, Bt);
    transW_kernel<<<dim3(NDIM/64, NHID/64), 256, 0, stream>>>(W1, W1t, NDIM, NHID);
    transW_kernel<<<dim3(NHID/64, NDIM/64), 256, 0, stream>>>(W2, W2t, NHID, NDIM);
    finit_h_kernel<<<NBATCH, 512, 0, stream>>>(y_init, W1, b1, t_eval, h1);
    finit_rest_kernel<<<NBATCH, 256, 0, stream>>>(y_init, W2, b2, h1, inv0, M2, yf2i, yM2);

    const int M = NBATCH * NP; // 32768
    for (int it = 0; it < MAXIT; ++it) {
        kernelA<<<NBATCH, 256, 0, stream>>>(PhiT, pd2i, yf2i, Bt, Ygb, done);
        mfma_gemm<<<dim3(M/128, NHID/128), 256, 0, stream>>>(Ygb, W1t, (void*)Hb, M, NHID, NDIM, b1, tcheb, done, 1);
        gemm2_fused<<<dim3(M/128, NDIM/128), 256, 0, stream>>>(Hb, W2t, b2, pqh, pql, yM2, Bt,
                                                               accum, counter, done, out + OUT_DELTA);
    }
    kernelEpi<<<NBATCH, 256, 0, stream>>>(PhiOut, pd2i, yf2i, Bt, out + OUT_TRAJ, out + OUT_B);
}